// Round 2
// baseline (239.889 us; speedup 1.0000x reference)
//
#include <hip/hip_runtime.h>

// Problem: y[b, n*DOUT+o] = sum_i x[b,n,i] * W[n,i,o] + bias[n,o]
// B=2048, N=64, DIN=512, DOUT=512, all fp32.
// Strategy: bf16 MFMA (fp32 accum). Pre-pass transposes W -> Wt bf16 [N][DOUT][DIN]
// in d_ws (needs 64*512*512*2 = 33,554,432 bytes). Main GEMM: 128x128 tile,
// BK=32, double-buffered LDS, reg-staged A (fp32->bf16 cvt fused).

#define NN 64
#define DIN 512
#define DOUT 512
#define BM 128
#define BN 128
#define BK 32
#define LDK 40                    // padded row (shorts): 80B stride, 16B aligned
#define ROWSTRIDE (NN * DIN)      // x row stride in floats (32768)
#define OUTSTRIDE (NN * DOUT)     // out row stride in floats (32768)

typedef __bf16 bf16x8 __attribute__((ext_vector_type(8)));
typedef float f32x4 __attribute__((ext_vector_type(4)));

// fp32 -> bf16 round-to-nearest-even, pure bit ops (no HIP class types)
__device__ __forceinline__ unsigned int f2bf_bits(float f) {
    unsigned int u = __builtin_bit_cast(unsigned int, f);
    return (u + 0x7fffu + ((u >> 16) & 1u)) >> 16;
}

__device__ __forceinline__ unsigned short f2bf(float f) {
    return (unsigned short)f2bf_bits(f);
}

__device__ __forceinline__ unsigned int f2bf2(float a, float b) {
    return f2bf_bits(a) | (f2bf_bits(b) << 16);
}

// ---- pre-pass: Wt[n][o][i] = bf16(W[n][i][o]) ----
__global__ void wt_transpose_kernel(const float* __restrict__ W,
                                    unsigned short* __restrict__ Wt) {
    __shared__ float tile[32][33];
    const int n  = blockIdx.z;
    const int i0 = blockIdx.x * 32;
    const int o0 = blockIdx.y * 32;
    const float* Wn = W + (size_t)n * DIN * DOUT;
    unsigned short* Wtn = Wt + (size_t)n * DIN * DOUT;
    const int tx = threadIdx.x, ty = threadIdx.y;
#pragma unroll
    for (int q = 0; q < 4; ++q)
        tile[ty + q * 8][tx] = Wn[(size_t)(i0 + ty + q * 8) * DOUT + (o0 + tx)];
    __syncthreads();
#pragma unroll
    for (int q = 0; q < 4; ++q)
        Wtn[(size_t)(o0 + ty + q * 8) * DIN + (i0 + tx)] = f2bf(tile[tx][ty + q * 8]);
}

// ---- main GEMM: per node n, C[2048,512] = X_n[2048,512] @ W_n[512,512] + b_n ----
__global__ __launch_bounds__(256) void node_gemm_kernel(
    const float* __restrict__ X, const unsigned short* __restrict__ Wt,
    const float* __restrict__ Bias, float* __restrict__ Out) {
    __shared__ unsigned short As[2][BM][LDK];
    __shared__ unsigned short Bs[2][BN][LDK];

    // 4096 WGs: bijective XCD swizzle (4096 % 8 == 0) -> 8 nodes per XCD chunk
    const int bid = blockIdx.x;
    const int swz = (bid & 7) * 512 + (bid >> 3);
    const int node  = swz >> 6;
    const int rem   = swz & 63;
    const int mtile = rem >> 2;
    const int ntile = rem & 3;
    const int brow = mtile * BM;
    const int bcol = ntile * BN;

    const int tid  = threadIdx.x;
    const int lane = tid & 63;
    const int wave = tid >> 6;
    const int wm = wave >> 1, wn = wave & 1;

    const float* Xb = X + (size_t)brow * ROWSTRIDE + node * DIN;
    const unsigned short* Wb = Wt + (size_t)node * DIN * DOUT + (size_t)bcol * DIN;

    // staging coords: A: 1024 float4 -> 4/thread; B: 512 x 16B -> 2/thread
    const int a_r = tid >> 3, a_c = tid & 7;  // rows +q*32, col4
    const int b_r = tid >> 2, b_c = tid & 3;  // rows +q*64, 16B chunk

    // fragment LDS offsets (shorts)
    const int aoff = (wm * 64 + (lane & 15)) * LDK + (lane >> 4) * 8;
    const int boff = (wn * 64 + (lane & 15)) * LDK + (lane >> 4) * 8;

    f32x4 acc[4][4] = {};

    float4 arg[4];
    int4   brg[2];

    // prologue: tile 0
#pragma unroll
    for (int q = 0; q < 4; ++q)
        arg[q] = *reinterpret_cast<const float4*>(Xb + (size_t)(a_r + q * 32) * ROWSTRIDE + a_c * 4);
#pragma unroll
    for (int q = 0; q < 2; ++q)
        brg[q] = *reinterpret_cast<const int4*>(Wb + (b_r + q * 64) * DIN + b_c * 8);
#pragma unroll
    for (int q = 0; q < 4; ++q) {
        uint2 p;
        p.x = f2bf2(arg[q].x, arg[q].y);
        p.y = f2bf2(arg[q].z, arg[q].w);
        *reinterpret_cast<uint2*>(&As[0][a_r + q * 32][a_c * 4]) = p;
    }
#pragma unroll
    for (int q = 0; q < 2; ++q)
        *reinterpret_cast<int4*>(&Bs[0][b_r + q * 64][b_c * 8]) = brg[q];
    __syncthreads();

    int cur = 0;
    for (int kt = 0; kt < DIN / BK; ++kt) {
        const int k0n = (kt + 1) * BK;
        const bool more = (kt < DIN / BK - 1);
        if (more) {  // issue next-tile global loads early (hide under MFMA)
#pragma unroll
            for (int q = 0; q < 4; ++q)
                arg[q] = *reinterpret_cast<const float4*>(
                    Xb + (size_t)(a_r + q * 32) * ROWSTRIDE + k0n + a_c * 4);
#pragma unroll
            for (int q = 0; q < 2; ++q)
                brg[q] = *reinterpret_cast<const int4*>(Wb + (b_r + q * 64) * DIN + k0n + b_c * 8);
        }

        // compute current tile
        const unsigned short* Abase = &As[cur][0][0];
        const unsigned short* Bbase = &Bs[cur][0][0];
        bf16x8 af[4], bq[4];
#pragma unroll
        for (int m = 0; m < 4; ++m)
            af[m] = *reinterpret_cast<const bf16x8*>(Abase + aoff + m * 16 * LDK);
#pragma unroll
        for (int n = 0; n < 4; ++n)
            bq[n] = *reinterpret_cast<const bf16x8*>(Bbase + boff + n * 16 * LDK);
#pragma unroll
        for (int m = 0; m < 4; ++m)
#pragma unroll
            for (int n = 0; n < 4; ++n)
                acc[m][n] = __builtin_amdgcn_mfma_f32_16x16x32_bf16(af[m], bq[n], acc[m][n], 0, 0, 0);

        if (more) {  // cvt + write next tile into the other buffer
#pragma unroll
            for (int q = 0; q < 4; ++q) {
                uint2 p;
                p.x = f2bf2(arg[q].x, arg[q].y);
                p.y = f2bf2(arg[q].z, arg[q].w);
                *reinterpret_cast<uint2*>(&As[cur ^ 1][a_r + q * 32][a_c * 4]) = p;
            }
#pragma unroll
            for (int q = 0; q < 2; ++q)
                *reinterpret_cast<int4*>(&Bs[cur ^ 1][b_r + q * 64][b_c * 8]) = brg[q];
        }
        __syncthreads();
        cur ^= 1;
    }

    // epilogue: D mapping col = lane&15, row = (lane>>4)*4 + j  (m89/m91-verified)
    const float* bn = Bias + node * DOUT;
    float* outb = Out + (size_t)brow * OUTSTRIDE + node * DOUT;
#pragma unroll
    for (int n = 0; n < 4; ++n) {
        const int col = bcol + wn * 64 + n * 16 + (lane & 15);
        const float bias = bn[col];
#pragma unroll
        for (int m = 0; m < 4; ++m) {
            const int r0 = wm * 64 + m * 16 + ((lane >> 4) << 2);
#pragma unroll
            for (int j = 0; j < 4; ++j)
                outb[(size_t)(r0 + j) * OUTSTRIDE + col] = acc[m][n][j] + bias;
        }
    }
}

extern "C" void kernel_launch(void* const* d_in, const int* in_sizes, int n_in,
                              void* d_out, int out_size, void* d_ws, size_t ws_size,
                              hipStream_t stream) {
    const float* x = (const float*)d_in[0];    // [2048, 64, 512]
    const float* W = (const float*)d_in[1];    // [64, 512, 512]
    const float* b = (const float*)d_in[2];    // [64, 512]
    float* out = (float*)d_out;                // [2048, 64*512]
    unsigned short* Wt = (unsigned short*)d_ws;  // bf16 [64][512][512] = 33.5 MB

    wt_transpose_kernel<<<dim3(DIN / 32, DOUT / 32, NN), dim3(32, 8), 0, stream>>>(W, Wt);
    node_gemm_kernel<<<dim3(4096), dim3(256), 0, stream>>>(x, Wt, b, out);
}

// Round 3
// 235.413 us; speedup vs baseline: 1.0190x; 1.0190x over previous
//
#include <hip/hip_runtime.h>

// y[b, n*DOUT+o] = sum_i x[b,n,i] * W[n,i,o] + bias[n,o]
// B=2048, N=64, DIN=512, DOUT=512, fp32 in/out, bf16 MFMA (fp32 accum).
// R3: B-operand via global_load_lds(16) with source-swizzled layout,
// native bf16 cvt for A, BN=256 (4 waves, wave-per-64col), LDS 43KB -> 3 blk/CU.

#define NN 64
#define DIN 512
#define DOUT 512
#define BM 64
#define BN 256
#define BK 32
#define LDK 40                    // A row pitch in shorts (80B): 2-way reads = free
#define ROWSTRIDE (NN * DIN)
#define OUTSTRIDE (NN * DOUT)
#define KSTEPS (DIN / BK)         // 16

typedef __bf16 bf16x8 __attribute__((ext_vector_type(8)));
typedef float f32x4 __attribute__((ext_vector_type(4)));

__device__ __forceinline__ unsigned short f2bf(float f) {
    return __builtin_bit_cast(unsigned short, (__bf16)f);  // RNE; compiler fuses to v_cvt_pk_bf16_f32
}
__device__ __forceinline__ unsigned int f2bf2(float a, float b) {
    return (unsigned int)f2bf(a) | ((unsigned int)f2bf(b) << 16);
}

typedef const __attribute__((address_space(1))) unsigned int* gas1_t;
typedef __attribute__((address_space(3))) unsigned int* las3_t;
__device__ __forceinline__ void gload_lds16(const void* g, void* l) {
    // LDS dest is wave-uniform base + lane*16 (m104); global src is per-lane.
    __builtin_amdgcn_global_load_lds((gas1_t)g, (las3_t)l, 16, 0, 0);
}

// ---- pre-pass: Wt[n][o][i] = bf16(W[n][i][o]) ----
__global__ void wt_transpose_kernel(const float* __restrict__ W,
                                    unsigned short* __restrict__ Wt) {
    __shared__ float tile[32][33];
    const int n  = blockIdx.z;
    const int i0 = blockIdx.x * 32;
    const int o0 = blockIdx.y * 32;
    const float* Wn = W + (size_t)n * DIN * DOUT;
    unsigned short* Wtn = Wt + (size_t)n * DIN * DOUT;
    const int tx = threadIdx.x, ty = threadIdx.y;
#pragma unroll
    for (int q = 0; q < 4; ++q)
        tile[ty + q * 8][tx] = Wn[(size_t)(i0 + ty + q * 8) * DOUT + (o0 + tx)];
    __syncthreads();
#pragma unroll
    for (int q = 0; q < 4; ++q)
        Wtn[(size_t)(o0 + ty + q * 8) * DIN + (i0 + tx)] = f2bf(tile[tx][ty + q * 8]);
}

// ---- main GEMM ----
__global__ __launch_bounds__(256) void node_gemm_kernel(
    const float* __restrict__ X, const unsigned short* __restrict__ Wt,
    const float* __restrict__ Bias, float* __restrict__ Out) {
    __shared__ unsigned short As[2][BM * LDK];   // 2 x 5120 B
    __shared__ unsigned short Bs[2][BN * BK];    // 2 x 16384 B (linear rows of 64B, slot-swizzled content)

    // 4096 WGs, bijective XCD swizzle (4096 % 8 == 0): 64 blocks/node contiguous per XCD
    const int bid = blockIdx.x;
    const int swz = (bid & 7) * 512 + (bid >> 3);
    const int node  = swz >> 6;
    const int rem   = swz & 63;
    const int mtile = rem >> 1;       // consecutive pair shares x-panel (L2)
    const int ntile = rem & 1;
    const int brow = mtile * BM;
    const int bcol = ntile * BN;

    const int tid  = threadIdx.x;
    const int lane = tid & 63;
    const int w    = tid >> 6;        // wave 0..3, owns cols 64w..64w+63

    const float* Xb = X + (size_t)brow * ROWSTRIDE + node * DIN;
    const unsigned short* Wb = Wt + (size_t)node * DIN * DOUT + (size_t)bcol * DIN;

    // B staging (global_load_lds): 16 chunks of 1KB; chunk cb = q*4+w covers rows 16cb..16cb+15
    const int b_rl = lane >> 2;       // row within chunk
    const int b_cs = lane & 3;        // dest 16B slot within 64B row

    // A staging (reg + cvt): thread -> row a_r, 16B slot a_c (8 shorts = 8 floats)
    const int a_r = tid >> 2;         // 0..63
    const int a_c = tid & 3;          // 0..3

    // fragment offsets
    const int arow = lane & 15;
    const int akk  = lane >> 4;
    const int aoff = arow * LDK + akk * 8;
    const int obase = w * 64 + (lane & 15);
    const int bswz  = akk ^ ((obase >> 1) & 3);          // matches stage-side slot swizzle
    const int boff  = obase * BK + bswz * 8;

    f32x4 acc[4][4] = {};
    float4 av0, av1;

    auto stageB = [&](int buf, int k0) {
#pragma unroll
        for (int q = 0; q < 4; ++q) {
            const int cb = q * 4 + w;                     // wave-uniform
            const int r  = cb * 16 + b_rl;                // 0..255
            const int c  = b_cs ^ ((r >> 1) & 3);         // inverse-swizzled source chunk
            gload_lds16(Wb + (size_t)r * DIN + k0 + c * 8, &Bs[buf][cb * 512]);
        }
    };
    auto loadA = [&](int k0) {
        const float* p = Xb + (size_t)a_r * ROWSTRIDE + k0 + a_c * 8;
        av0 = *reinterpret_cast<const float4*>(p);
        av1 = *reinterpret_cast<const float4*>(p + 4);
    };
    auto storeA = [&](int buf) {
        uint4 pk;
        pk.x = f2bf2(av0.x, av0.y);
        pk.y = f2bf2(av0.z, av0.w);
        pk.z = f2bf2(av1.x, av1.y);
        pk.w = f2bf2(av1.z, av1.w);
        *reinterpret_cast<uint4*>(&As[buf][a_r * LDK + a_c * 8]) = pk;
    };

    // prologue
    loadA(0);
    stageB(0, 0);
    storeA(0);
    __syncthreads();

    int buf = 0;
    for (int kt = 0; kt < KSTEPS; ++kt) {
        const bool more = (kt < KSTEPS - 1);
        if (more) {                        // issue next-tile loads before compute
            stageB(buf ^ 1, (kt + 1) * BK);
            loadA((kt + 1) * BK);
        }
        bf16x8 af[4], bq[4];
#pragma unroll
        for (int m = 0; m < 4; ++m)
            af[m] = *reinterpret_cast<const bf16x8*>(&As[buf][aoff + m * 16 * LDK]);
#pragma unroll
        for (int n = 0; n < 4; ++n)
            bq[n] = *reinterpret_cast<const bf16x8*>(&Bs[buf][boff + n * 16 * BK]);
#pragma unroll
        for (int m = 0; m < 4; ++m)
#pragma unroll
            for (int n = 0; n < 4; ++n)
                acc[m][n] = __builtin_amdgcn_mfma_f32_16x16x32_bf16(af[m], bq[n], acc[m][n], 0, 0, 0);
        if (more) storeA(buf ^ 1);         // cvt after MFMA hides global latency
        __syncthreads();
        buf ^= 1;
    }

    // epilogue: D mapping col = lane&15, row = (lane>>4)*4 + j
    const float* bn = Bias + node * DOUT + bcol;
    float* outb = Out + (size_t)brow * OUTSTRIDE + node * DOUT + bcol;
#pragma unroll
    for (int n = 0; n < 4; ++n) {
        const int col = w * 64 + n * 16 + (lane & 15);
        const float bias = bn[col];
#pragma unroll
        for (int m = 0; m < 4; ++m) {
            const int r0 = m * 16 + akk * 4;
#pragma unroll
            for (int j = 0; j < 4; ++j)
                outb[(size_t)(r0 + j) * OUTSTRIDE + col] = acc[m][n][j] + bias;
        }
    }
}

extern "C" void kernel_launch(void* const* d_in, const int* in_sizes, int n_in,
                              void* d_out, int out_size, void* d_ws, size_t ws_size,
                              hipStream_t stream) {
    const float* x = (const float*)d_in[0];      // [2048, 64, 512]
    const float* W = (const float*)d_in[1];      // [64, 512, 512]
    const float* b = (const float*)d_in[2];      // [64, 512]
    float* out = (float*)d_out;                  // [2048, 64*512]
    unsigned short* Wt = (unsigned short*)d_ws;  // bf16 [64][512][512] = 33.5 MB

    wt_transpose_kernel<<<dim3(DIN / 32, DOUT / 32, NN), dim3(32, 8), 0, stream>>>(W, Wt);
    node_gemm_kernel<<<dim3(4096), dim3(256), 0, stream>>>(x, Wt, b, out);
}